// Round 19
// baseline (156.653 us; speedup 1.0000x reference)
//
#include <hip/hip_runtime.h>
#include <hip/hip_bf16.h>
#include <stdint.h>

#define NTOK 4096
#define DM   512
#define HD   2048
#define NE   8

typedef __bf16 bf16x8 __attribute__((ext_vector_type(8)));
typedef float  f32x4  __attribute__((ext_vector_type(4)));

__device__ __forceinline__ unsigned short f2bf(float f) {
  unsigned int u = __float_as_uint(f);
  u += 0x7FFF + ((u >> 16) & 1);   // RTNE
  return (unsigned short)(u >> 16);
}

__device__ __forceinline__ float gelu_fast(float x) {
  float s = 1.5957691216f * (x + 0.044715f * x * x * x);
  return x / (1.f + __expf(-s));
}

__device__ __forceinline__ void gload_lds16(const void* g, void* l) {
  __builtin_amdgcn_global_load_lds(
      (__attribute__((address_space(1))) const void*)g,
      (__attribute__((address_space(3))) void*)l,
      16, 0, 0);
}

// ---------- W[e][K][N] fp32 -> WT[e][N][K] bf16 transpose (device body) ----------
template<int K, int N>
__device__ __forceinline__ void transw_dev(
    const float* __restrict__ in, unsigned short* __restrict__ out,
    int bid, int t, float (*tile)[33]) {
  const int tpe = (K / 32) * (N / 32);
  int e   = bid / tpe;
  int rem = bid % tpe;
  int kt  = rem / (N / 32), nt = rem % (N / 32);
  int tx  = t & 31, ty = t >> 5;
  const float* src = in + ((size_t)e * K + kt * 32) * N + (size_t)nt * 32;
  #pragma unroll
  for (int i = 0; i < 4; i++) {
    int r = ty + i * 8;
    tile[r][tx] = src[(size_t)r * N + tx];
  }
  __syncthreads();
  unsigned short* dst = out + ((size_t)e * N + nt * 32) * K + (size_t)kt * 32;
  #pragma unroll
  for (int i = 0; i < 4; i++) {
    int rr = ty + i * 8;
    dst[(size_t)rr * K + tx] = f2bf(tile[tx][rr]);
  }
}

// ---------- fused prep: convx | transw1 | transw2 | gate ----------
__global__ __launch_bounds__(256) void prep_kernel(
    const float* __restrict__ inp, const float* __restrict__ w1,
    const float* __restrict__ w2, const float* __restrict__ gw,
    const float* __restrict__ gb, unsigned short* __restrict__ Xb,
    unsigned short* __restrict__ W1T, unsigned short* __restrict__ W2T,
    int* __restrict__ eidx, float* __restrict__ wgtA) {
  __shared__ float tile[32][33];
  const int b = blockIdx.x;
  const int t = threadIdx.x;

  if (b < 1024) {                     // ---- convx
    int i = b * 256 + t;
    const f32x4* p = (const f32x4*)(inp + (size_t)i * 8);
    f32x4 v0 = p[0], v1 = p[1];
    union { unsigned short s[8]; uint4 u; } o;
    #pragma unroll
    for (int j = 0; j < 4; j++) { o.s[j] = f2bf(v0[j]); o.s[4 + j] = f2bf(v1[j]); }
    *(uint4*)(Xb + (size_t)i * 8) = o.u;
  } else if (b < 9216) {              // ---- transpose w1
    transw_dev<DM, HD>(w1, W1T, b - 1024, t, tile);
  } else if (b < 17408) {             // ---- transpose w2
    transw_dev<HD, DM>(w2, W2T, b - 9216, t, tile);
  } else {                            // ---- gate
    int tok = (b - 17408) * 4 + (t >> 6);
    int l   = t & 63;
    const float* x = inp + (size_t)tok * DM;
    float acc[NE];
    #pragma unroll
    for (int e = 0; e < NE; e++) acc[e] = 0.f;
    #pragma unroll
    for (int j = 0; j < DM / 64; j++) {
      int d = j * 64 + l;
      float xv = x[d];
      const float* g = gw + (size_t)d * NE;
      #pragma unroll
      for (int e = 0; e < NE; e++) acc[e] += xv * g[e];
    }
    #pragma unroll
    for (int off = 32; off >= 1; off >>= 1) {
      #pragma unroll
      for (int e = 0; e < NE; e++) acc[e] += __shfl_xor(acc[e], off, 64);
    }
    if (l == 0) {
      float lg[NE];
      #pragma unroll
      for (int e = 0; e < NE; e++) lg[e] = acc[e] + gb[e];
      int i0 = 0;
      #pragma unroll
      for (int e = 1; e < NE; e++) if (lg[e] > lg[i0]) i0 = e;
      int i1 = (i0 == 0) ? 1 : 0;
      #pragma unroll
      for (int e = 0; e < NE; e++) if (e != i0 && lg[e] > lg[i1]) i1 = e;
      float ev = expf(lg[i1] - lg[i0]);
      float w0 = 1.f / (1.f + ev);
      float w1s = ev * w0;
      wgtA[tok * 2]     = w0;
      wgtA[tok * 2 + 1] = w1s;
      eidx[tok * 2]     = i0;
      eidx[tok * 2 + 1] = i1;
    }
  }
}

// ---------- build per-expert entry lists ----------
__global__ __launch_bounds__(256) void build_lists(
    const int* __restrict__ eidx, int* __restrict__ lists,
    int* __restrict__ counts) {
  __shared__ int wsums[4];
  __shared__ int base;
  const int e = blockIdx.x;
  const int t = threadIdx.x;
  const int lane = t & 63, w = t >> 6;
  if (t == 0) base = 0;
  __syncthreads();
  for (int it = 0; it < 2 * NTOK / 256; ++it) {
    int i = it * 256 + t;
    int match = (eidx[i] == e) ? 1 : 0;
    unsigned long long b = __ballot(match);
    int wsum = __popcll(b);
    int lpre = __popcll(b & ((1ull << lane) - 1ull));
    if (lane == 0) wsums[w] = wsum;
    __syncthreads();
    int wpre = 0;
    #pragma unroll
    for (int k = 0; k < 4; k++) if (k < w) wpre += wsums[k];
    int tot = wsums[0] + wsums[1] + wsums[2] + wsums[3];
    if (match) lists[e * NTOK + base + wpre + lpre] = i;
    __syncthreads();
    if (t == 0) base += tot;
    __syncthreads();
  }
  if (t == 0) counts[e] = base;
}

// ---------- gathered GEMM: 256x256 tile, BK=128, 16 waves + dense LDS epilogue ----------
// Staged bytes = M*N*K*2*(1/BM+1/BN): 256x256 is the minimum (-33% vs 256x128).
// 16 waves (1024 thr), wave tile 64x64 -> per-thread state identical to R18 (~70 VGPR,
// 16 waves/CU). LDS 129KB single-buffer, NKT=4. Epilogue: whole 256x256 bf16 output
// tile staged in the 128KB LDS, then dense 512B-row stores.
template<int KDIM, int NDIM, bool IS_L1, int KSPLIT>
__global__ __launch_bounds__(1024) void moe_gemm(
    const unsigned short* __restrict__ A,
    const unsigned short* __restrict__ WT,     // [E][NDIM][KDIM] bf16
    const float* __restrict__ bias,            // [E][NDIM] (L1 only)
    const int* __restrict__ lists,             // [E][NTOK]
    const int* __restrict__ counts,            // [E]
    unsigned short* __restrict__ Hout) {       // [KSPLIT][8192][NDIM] bf16
  __shared__ __align__(16) char smem[132096];  // A 64K | B 64K | E 1K
  unsigned short* ldsA = (unsigned short*)smem;            // [256][128]
  unsigned short* ldsB = (unsigned short*)(smem + 65536);  // [256][128]
  int* ldsE = (int*)(smem + 131072);                       // [256]

  const int CT  = NDIM / 256;
  const int e   = blockIdx.x & 7;              // expert == XCD
  const int idx = blockIdx.x >> 3;
  const int ct  = idx % CT;
  const int r1  = idx / CT;
  const int ks  = r1 % KSPLIT;
  const int rt  = r1 / KSPLIT;
  const int cnt = counts[e];
  if (rt * 256 >= cnt) return;

  const int t = threadIdx.x;
  if (t < 256) {
    int rg = rt * 256 + t;
    ldsE[t] = lists[e * NTOK + (rg < cnt ? rg : cnt - 1)];
  }
  __syncthreads();

  const int lane = t & 63;
  const int wid  = t >> 6;                     // 0..15
  const int wr = wid >> 2, wc = wid & 3;       // 4x4 wave grid, 64x64 tiles
  const int l15 = lane & 15;
  const int rowsel = t >> 4;                   // 0..63
  const int colsel = (t & 15) ^ (rowsel & 7);  // inverse-swizzled 16B chunk

  const int KCH = KDIM / KSPLIT;
  const unsigned short* aptr[4];
  const unsigned short* bptr[4];
  #pragma unroll
  for (int i = 0; i < 4; i++) {
    int rl = i * 64 + rowsel;
    int entry = ldsE[rl];
    long arow = IS_L1 ? (entry >> 1) : entry;
    aptr[i] = A + arow * (long)KDIM + ks * KCH + colsel * 8;
    int brow = ct * 256 + rl;
    bptr[i] = WT + ((long)e * NDIM + brow) * KDIM + ks * KCH + colsel * 8;
  }

  f32x4 acc[4][4] = {};
  const int NKT = KCH / 128;                   // 4 (L1, L2-ks4) or 8 (L2-ks2)

  for (int kt = 0; kt < NKT; ++kt) {
    #pragma unroll
    for (int i = 0; i < 4; i++) {
      gload_lds16(aptr[i] + kt * 128, smem + i * 16384 + t * 16);
      gload_lds16(bptr[i] + kt * 128, smem + 65536 + i * 16384 + t * 16);
    }
    __syncthreads();
    #pragma unroll
    for (int kk = 0; kk < 4; ++kk) {
      bf16x8 a[4], b[4];
      int ko = kk * 32 + (lane >> 4) * 8;
      #pragma unroll
      for (int m = 0; m < 4; m++) {
        int rx = wr * 64 + m * 16 + l15;
        a[m] = *(const bf16x8*)&ldsA[rx * 128 + (ko ^ ((rx & 7) << 3))];
      }
      #pragma unroll
      for (int n = 0; n < 4; n++) {
        int rx = wc * 64 + n * 16 + l15;
        b[n] = *(const bf16x8*)&ldsB[rx * 128 + (ko ^ ((rx & 7) << 3))];
      }
      #pragma unroll
      for (int m = 0; m < 4; m++)
        #pragma unroll
        for (int n = 0; n < 4; n++)
          acc[m][n] = __builtin_amdgcn_mfma_f32_16x16x32_bf16(a[m], b[n], acc[m][n], 0, 0, 0);
    }
    __syncthreads();
  }

  // ---- dense epilogue: full 256x256 bf16 tile in LDS (128KB), then 512B rows ----
  float bv[4];
  #pragma unroll
  for (int n = 0; n < 4; n++)
    bv[n] = IS_L1 ? bias[e * NDIM + ct * 256 + wc * 64 + n * 16 + l15] : 0.f;
  unsigned short* ldsO = (unsigned short*)smem;            // [256][256]
  unsigned short* Hbase = Hout + (size_t)ks * 8192 * NDIM;

  #pragma unroll
  for (int m = 0; m < 4; m++) {
    int row = wr * 64 + m * 16 + (lane >> 4) * 4;
    #pragma unroll
    for (int n = 0; n < 4; n++) {
      int col = wc * 64 + n * 16 + l15;
      #pragma unroll
      for (int r = 0; r < 4; r++) {
        float v = acc[m][n][r] + bv[n];
        ldsO[(row + r) * 256 + col] = f2bf(IS_L1 ? gelu_fast(v) : v);
      }
    }
  }
  __syncthreads();

  #pragma unroll
  for (int rnd = 0; rnd < 8; ++rnd) {
    int row = rnd * 32 + (t >> 5);
    if (rt * 256 + row >= cnt) continue;
    int ent = ldsE[row];
    int ch  = t & 31;
    uint4 v = *(const uint4*)&ldsO[row * 256 + ch * 8];
    *(uint4*)(Hbase + (size_t)ent * NDIM + ct * 256 + ch * 8) = v;
  }
}

// ---------- combine: out[tok] = sum_slot w_s * (sum_ks Y[ks][ent] + b2[e_s]) ----------
template<int NKS>
__global__ __launch_bounds__(256) void combine_kernel(
    const unsigned short* __restrict__ Y,      // [NKS][8192][512] bf16
    const float* __restrict__ b2,              // [8][512]
    const int* __restrict__ eidx,              // [8192]
    const float* __restrict__ wgtA,            // [8192]
    float* __restrict__ out) {
  const int t   = threadIdx.x;
  const int tok = blockIdx.x * 4 + (t >> 6);
  const int c0  = (t & 63) * 8;
  float o[8] = {};
  #pragma unroll
  for (int slot = 0; slot < 2; ++slot) {
    int ent = tok * 2 + slot;
    int es  = eidx[ent];
    float ws = wgtA[ent];
    float v[8] = {};
    #pragma unroll
    for (int ks = 0; ks < NKS; ++ks) {
      uint4 y = *(const uint4*)(Y + ((size_t)ks * 8192 + ent) * DM + c0);
      const unsigned short* s = (const unsigned short*)&y;
      #pragma unroll
      for (int j = 0; j < 8; j++) v[j] += __uint_as_float((unsigned)s[j] << 16);
    }
    const float* bb = b2 + (size_t)es * DM + c0;
    #pragma unroll
    for (int j = 0; j < 8; j++) o[j] += ws * (v[j] + bb[j]);
  }
  *(f32x4*)(out + (size_t)tok * DM + c0)     = *(f32x4*)&o[0];
  *(f32x4*)(out + (size_t)tok * DM + c0 + 4) = *(f32x4*)&o[4];
}

extern "C" void kernel_launch(void* const* d_in, const int* in_sizes, int n_in,
                              void* d_out, int out_size, void* d_ws, size_t ws_size,
                              hipStream_t stream) {
  const float* inp = (const float*)d_in[0];
  const float* gw  = (const float*)d_in[1];
  const float* gb  = (const float*)d_in[2];
  const float* w1  = (const float*)d_in[3];
  const float* b1  = (const float*)d_in[4];
  const float* w2  = (const float*)d_in[5];
  const float* b2  = (const float*)d_in[6];
  float* out = (float*)d_out;

  char* ws = (char*)d_ws;
  unsigned short* Xb   = (unsigned short*)(ws + 0);          //  4 MiB
  unsigned short* W1T  = (unsigned short*)(ws + 4194304);    // 16 MiB
  unsigned short* W2T  = (unsigned short*)(ws + 20971520);   // 16 MiB
  unsigned short* Hbuf = (unsigned short*)(ws + 37748736);   // 32 MiB [8192][2048]
  int*   lists  = (int*)  (ws + 71303168);                   // [8][4096]
  float* wgtA   = (float*)(ws + 71434240);                   // [8192]
  int*   counts = (int*)  (ws + 71467008);                   // [8]
  int*   eidx   = (int*)  (ws + 71467072);                   // [8192]

  const size_t yfresh_off = 71499840;                        // 32-MiB Y[4]
  const bool bigws = ws_size >= yfresh_off + 4ull * 8192 * 512 * 2;

  prep_kernel<<<18432, 256, 0, stream>>>(inp, w1, w2, gw, gb,
                                         Xb, W1T, W2T, eidx, wgtA);
  build_lists<<<NE, 256, 0, stream>>>(eidx, lists, counts);
  // L1: 8e x 16rt x 8ct = 1024 blocks worst-case (~256 active), 1024 thr
  moe_gemm<DM, HD, true, 1><<<8 * 16 * (HD / 256), 1024, 0, stream>>>(
      Xb, W1T, b1, lists, counts, Hbuf);
  if (bigws) {
    unsigned short* Ybuf = (unsigned short*)(ws + yfresh_off);
    // L2: 8e x 16rt x 4ks x 2ct = 1024 blocks worst-case (~256 active)
    moe_gemm<HD, DM, false, 4><<<8 * 16 * 4 * (DM / 256), 1024, 0, stream>>>(
        Hbuf, W2T, b2, lists, counts, Ybuf);
    combine_kernel<4><<<NTOK / 4, 256, 0, stream>>>(Ybuf, b2, eidx, wgtA, out);
  } else {
    // fallback: Y[2] (16 MiB) aliases Xb+W1T (dead during L2; prep rewrites next call)
    unsigned short* Ybuf = (unsigned short*)(ws + 0);
    moe_gemm<HD, DM, false, 2><<<8 * 16 * 2 * (DM / 256), 1024, 0, stream>>>(
        Hbuf, W2T, b2, lists, counts, Ybuf);
    combine_kernel<2><<<NTOK / 4, 256, 0, stream>>>(Ybuf, b2, eidx, wgtA, out);
  }
}

// Round 21
// 116.242 us; speedup vs baseline: 1.3476x; 1.3476x over previous
//
#include <hip/hip_runtime.h>
#include <hip/hip_bf16.h>
#include <stdint.h>

#define NTOK 4096
#define DM   512
#define HD   2048
#define NE   8

typedef __bf16 bf16x8 __attribute__((ext_vector_type(8)));
typedef float  f32x4  __attribute__((ext_vector_type(4)));

__device__ __forceinline__ unsigned short f2bf(float f) {
  unsigned int u = __float_as_uint(f);
  u += 0x7FFF + ((u >> 16) & 1);   // RTNE
  return (unsigned short)(u >> 16);
}

__device__ __forceinline__ float gelu_fast(float x) {
  float s = 1.5957691216f * (x + 0.044715f * x * x * x);
  return x / (1.f + __expf(-s));
}

__device__ __forceinline__ void gload_lds16(const void* g, void* l) {
  __builtin_amdgcn_global_load_lds(
      (__attribute__((address_space(1))) const void*)g,
      (__attribute__((address_space(3))) void*)l,
      16, 0, 0);
}

// ---------- W[e][K][N] fp32 -> WT[e][N][K] bf16 transpose (device body) ----------
template<int K, int N>
__device__ __forceinline__ void transw_dev(
    const float* __restrict__ in, unsigned short* __restrict__ out,
    int bid, int t, float (*tile)[33]) {
  const int tpe = (K / 32) * (N / 32);
  int e   = bid / tpe;
  int rem = bid % tpe;
  int kt  = rem / (N / 32), nt = rem % (N / 32);
  int tx  = t & 31, ty = t >> 5;
  const float* src = in + ((size_t)e * K + kt * 32) * N + (size_t)nt * 32;
  #pragma unroll
  for (int i = 0; i < 4; i++) {
    int r = ty + i * 8;
    tile[r][tx] = src[(size_t)r * N + tx];
  }
  __syncthreads();
  unsigned short* dst = out + ((size_t)e * N + nt * 32) * K + (size_t)kt * 32;
  #pragma unroll
  for (int i = 0; i < 4; i++) {
    int rr = ty + i * 8;
    dst[(size_t)rr * K + tx] = f2bf(tile[tx][rr]);
  }
}

// ---------- fused prep: convx | transw1 | transw2 | gate ----------
__global__ __launch_bounds__(256) void prep_kernel(
    const float* __restrict__ inp, const float* __restrict__ w1,
    const float* __restrict__ w2, const float* __restrict__ gw,
    const float* __restrict__ gb, unsigned short* __restrict__ Xb,
    unsigned short* __restrict__ W1T, unsigned short* __restrict__ W2T,
    int* __restrict__ eidx, float* __restrict__ wgtA) {
  __shared__ float tile[32][33];
  const int b = blockIdx.x;
  const int t = threadIdx.x;

  if (b < 1024) {                     // ---- convx
    int i = b * 256 + t;
    const f32x4* p = (const f32x4*)(inp + (size_t)i * 8);
    f32x4 v0 = p[0], v1 = p[1];
    union { unsigned short s[8]; uint4 u; } o;
    #pragma unroll
    for (int j = 0; j < 4; j++) { o.s[j] = f2bf(v0[j]); o.s[4 + j] = f2bf(v1[j]); }
    *(uint4*)(Xb + (size_t)i * 8) = o.u;
  } else if (b < 9216) {              // ---- transpose w1
    transw_dev<DM, HD>(w1, W1T, b - 1024, t, tile);
  } else if (b < 17408) {             // ---- transpose w2
    transw_dev<HD, DM>(w2, W2T, b - 9216, t, tile);
  } else {                            // ---- gate
    int tok = (b - 17408) * 4 + (t >> 6);
    int l   = t & 63;
    const float* x = inp + (size_t)tok * DM;
    float acc[NE];
    #pragma unroll
    for (int e = 0; e < NE; e++) acc[e] = 0.f;
    #pragma unroll
    for (int j = 0; j < DM / 64; j++) {
      int d = j * 64 + l;
      float xv = x[d];
      const float* g = gw + (size_t)d * NE;
      #pragma unroll
      for (int e = 0; e < NE; e++) acc[e] += xv * g[e];
    }
    #pragma unroll
    for (int off = 32; off >= 1; off >>= 1) {
      #pragma unroll
      for (int e = 0; e < NE; e++) acc[e] += __shfl_xor(acc[e], off, 64);
    }
    if (l == 0) {
      float lg[NE];
      #pragma unroll
      for (int e = 0; e < NE; e++) lg[e] = acc[e] + gb[e];
      int i0 = 0;
      #pragma unroll
      for (int e = 1; e < NE; e++) if (lg[e] > lg[i0]) i0 = e;
      int i1 = (i0 == 0) ? 1 : 0;
      #pragma unroll
      for (int e = 0; e < NE; e++) if (e != i0 && lg[e] > lg[i1]) i1 = e;
      float ev = expf(lg[i1] - lg[i0]);
      float w0 = 1.f / (1.f + ev);
      float w1s = ev * w0;
      wgtA[tok * 2]     = w0;
      wgtA[tok * 2 + 1] = w1s;
      eidx[tok * 2]     = i0;
      eidx[tok * 2 + 1] = i1;
    }
  }
}

// ---------- build per-expert entry lists ----------
__global__ __launch_bounds__(256) void build_lists(
    const int* __restrict__ eidx, int* __restrict__ lists,
    int* __restrict__ counts) {
  __shared__ int wsums[4];
  __shared__ int base;
  const int e = blockIdx.x;
  const int t = threadIdx.x;
  const int lane = t & 63, w = t >> 6;
  if (t == 0) base = 0;
  __syncthreads();
  for (int it = 0; it < 2 * NTOK / 256; ++it) {
    int i = it * 256 + t;
    int match = (eidx[i] == e) ? 1 : 0;
    unsigned long long b = __ballot(match);
    int wsum = __popcll(b);
    int lpre = __popcll(b & ((1ull << lane) - 1ull));
    if (lane == 0) wsums[w] = wsum;
    __syncthreads();
    int wpre = 0;
    #pragma unroll
    for (int k = 0; k < 4; k++) if (k < w) wpre += wsums[k];
    int tot = wsums[0] + wsums[1] + wsums[2] + wsums[3];
    if (match) lists[e * NTOK + base + wpre + lpre] = i;
    __syncthreads();
    if (t == 0) base += tot;
    __syncthreads();
  }
  if (t == 0) counts[e] = base;
}

// ---------- gathered GEMM: 256x128 tile, BK=64, 8 waves + dense LDS epilogue ----------
// Measured optimum (R18): BM=256 halves W-panel refetch; dense epilogue removes the
// scattered-store wall (R17); XCD pin cuts FETCH (R10); T2 swizzle; 2-barrier loop.
// L1 (KSPLIT=1): Hout[entry][2048] = gelu(.+b1), entry-indexed.
// L2 (KSPLIT=2): Hout[ks][entry][512] = raw K-chunk matmul; combine sums.
template<int KDIM, int NDIM, bool IS_L1, int KSPLIT>
__global__ __launch_bounds__(512) void moe_gemm(
    const unsigned short* __restrict__ A,
    const unsigned short* __restrict__ WT,     // [E][NDIM][KDIM] bf16
    const float* __restrict__ bias,            // [E][NDIM] (L1 only)
    const int* __restrict__ lists,             // [E][NTOK]
    const int* __restrict__ counts,            // [E]
    unsigned short* __restrict__ Hout) {       // [KSPLIT][8192][NDIM] bf16
  __shared__ unsigned short ldsA[256 * 64];    // 32 KiB (reused as epilogue buf)
  __shared__ unsigned short ldsB[128 * 64];    // 16 KiB
  __shared__ int ldsE[256];

  const int CT  = NDIM / 128;
  const int e   = blockIdx.x & 7;              // expert == XCD
  const int idx = blockIdx.x >> 3;
  const int ct  = idx % CT;
  const int r1  = idx / CT;
  const int ks  = r1 % KSPLIT;
  const int rt  = r1 / KSPLIT;
  const int cnt = counts[e];
  if (rt * 256 >= cnt) return;

  const int t = threadIdx.x;
  if (t < 256) {
    int rg = rt * 256 + t;
    ldsE[t] = lists[e * NTOK + (rg < cnt ? rg : cnt - 1)];
  }
  __syncthreads();

  const int lane = t & 63;
  const int wid  = t >> 6;                     // 0..7
  const int wr = wid >> 1, wc = wid & 1;       // 4x2 wave grid, 64x64 each
  const int rowsel = t >> 3;                   // 0..63
  const int colsel = (t & 7) ^ (rowsel & 7);   // inverse-swizzled 16B source chunk

  const int KCH = KDIM / KSPLIT;               // 512 (L1) or 1024 (L2)
  const unsigned short* aptr[4];
  #pragma unroll
  for (int i = 0; i < 4; i++) {
    int rl = i * 64 + rowsel;
    int entry = ldsE[rl];
    long arow = IS_L1 ? (entry >> 1) : entry;
    aptr[i] = A + arow * (long)KDIM + ks * KCH + colsel * 8;
  }
  const unsigned short* bptr[2];
  #pragma unroll
  for (int j = 0; j < 2; j++) {
    int brow = ct * 128 + j * 64 + rowsel;
    bptr[j] = WT + ((long)e * NDIM + brow) * KDIM + ks * KCH + colsel * 8;
  }

  f32x4 acc[4][4] = {};
  const int NKT = KCH / 64;                    // 8 (L1) or 16 (L2)

  for (int kt = 0; kt < NKT; ++kt) {
    #pragma unroll
    for (int i = 0; i < 4; i++)
      gload_lds16(aptr[i] + kt * 64, (char*)ldsA + i * 8192 + t * 16);
    #pragma unroll
    for (int j = 0; j < 2; j++)
      gload_lds16(bptr[j] + kt * 64, (char*)ldsB + j * 8192 + t * 16);
    __syncthreads();
    #pragma unroll
    for (int kk = 0; kk < 2; ++kk) {
      bf16x8 a[4], b[4];
      int ko = kk * 32 + (lane >> 4) * 8;
      #pragma unroll
      for (int m = 0; m < 4; m++) {
        int rx = wr * 64 + m * 16 + (lane & 15);
        a[m] = *(const bf16x8*)&ldsA[rx * 64 + (ko ^ ((rx & 7) << 3))];
      }
      #pragma unroll
      for (int n = 0; n < 4; n++) {
        int rx = wc * 64 + n * 16 + (lane & 15);
        b[n] = *(const bf16x8*)&ldsB[rx * 64 + (ko ^ ((rx & 7) << 3))];
      }
      #pragma unroll
      for (int m = 0; m < 4; m++)
        #pragma unroll
        for (int n = 0; n < 4; n++)
          acc[m][n] = __builtin_amdgcn_mfma_f32_16x16x32_bf16(a[m], b[n], acc[m][n], 0, 0, 0);
    }
    __syncthreads();                           // releases ldsA/ldsB for next step/epilogue
  }

  // ---- dense epilogue in 2 halves of 128 rows through ldsA ([128][128] bf16) ----
  float bv[4];
  #pragma unroll
  for (int n = 0; n < 4; n++)
    bv[n] = IS_L1 ? bias[e * NDIM + ct * 128 + wc * 64 + n * 16 + (lane & 15)] : 0.f;
  unsigned short* ldsO = ldsA;
  unsigned short* Hbase = Hout + (size_t)ks * 8192 * NDIM;

  #pragma unroll
  for (int half = 0; half < 2; ++half) {
    if ((wr >> 1) == half) {                   // waves owning these 128 rows
      #pragma unroll
      for (int m = 0; m < 4; m++) {
        int lrow = (wr & 1) * 64 + m * 16 + (lane >> 4) * 4;
        #pragma unroll
        for (int n = 0; n < 4; n++) {
          int col = wc * 64 + n * 16 + (lane & 15);
          #pragma unroll
          for (int r = 0; r < 4; r++) {
            float v = acc[m][n][r] + bv[n];
            ldsO[(lrow + r) * 128 + col] = f2bf(IS_L1 ? gelu_fast(v) : v);
          }
        }
      }
    }
    __syncthreads();
    #pragma unroll
    for (int rnd = 0; rnd < 4; ++rnd) {        // dense 256B-row stores
      int lrow = rnd * 32 + (t >> 4);
      int row  = half * 128 + lrow;
      if (rt * 256 + row < cnt) {
        int ent = ldsE[row];
        int ch  = t & 15;
        uint4 v = *(const uint4*)&ldsO[lrow * 128 + ch * 8];
        *(uint4*)(Hbase + (size_t)ent * NDIM + ct * 128 + ch * 8) = v;
      }
    }
    __syncthreads();                           // protect ldsO before next half
  }
}

// ---------- combine: out[tok] = sum_slot w_s * (sum_ks Y[ks][ent] + b2[e_s]) ----------
__global__ __launch_bounds__(256) void combine_kernel(
    const unsigned short* __restrict__ Y,      // [2][8192][512] bf16
    const float* __restrict__ b2,              // [8][512]
    const int* __restrict__ eidx,              // [8192]
    const float* __restrict__ wgtA,            // [8192]
    float* __restrict__ out) {
  const int t   = threadIdx.x;
  const int tok = blockIdx.x * 4 + (t >> 6);
  const int c0  = (t & 63) * 8;
  float o[8] = {};
  #pragma unroll
  for (int slot = 0; slot < 2; ++slot) {
    int ent = tok * 2 + slot;
    int es  = eidx[ent];
    float ws = wgtA[ent];
    uint4 y0 = *(const uint4*)(Y + (size_t)ent * DM + c0);
    uint4 y1 = *(const uint4*)(Y + (size_t)(8192 + ent) * DM + c0);
    const unsigned short* s0 = (const unsigned short*)&y0;
    const unsigned short* s1 = (const unsigned short*)&y1;
    const float* bb = b2 + (size_t)es * DM + c0;
    #pragma unroll
    for (int j = 0; j < 8; j++) {
      float v = __uint_as_float((unsigned)s0[j] << 16)
              + __uint_as_float((unsigned)s1[j] << 16);
      o[j] += ws * (v + bb[j]);
    }
  }
  *(f32x4*)(out + (size_t)tok * DM + c0)     = *(f32x4*)&o[0];
  *(f32x4*)(out + (size_t)tok * DM + c0 + 4) = *(f32x4*)&o[4];
}

extern "C" void kernel_launch(void* const* d_in, const int* in_sizes, int n_in,
                              void* d_out, int out_size, void* d_ws, size_t ws_size,
                              hipStream_t stream) {
  const float* inp = (const float*)d_in[0];
  const float* gw  = (const float*)d_in[1];
  const float* gb  = (const float*)d_in[2];
  const float* w1  = (const float*)d_in[3];
  const float* b1  = (const float*)d_in[4];
  const float* w2  = (const float*)d_in[5];
  const float* b2  = (const float*)d_in[6];
  float* out = (float*)d_out;

  char* ws = (char*)d_ws;
  unsigned short* Xb   = (unsigned short*)(ws + 0);          //  4 MiB
  unsigned short* W1T  = (unsigned short*)(ws + 4194304);    // 16 MiB
  unsigned short* W2T  = (unsigned short*)(ws + 20971520);   // 16 MiB
  unsigned short* Hbuf = (unsigned short*)(ws + 37748736);   // 32 MiB [8192][2048]
  int*   lists  = (int*)  (ws + 71303168);                   // [8][4096]
  float* wgtA   = (float*)(ws + 71434240);                   // [8192]
  int*   counts = (int*)  (ws + 71467008);                   // [8]
  int*   eidx   = (int*)  (ws + 71467072);                   // [8192]
  // Y[2][8192][512] bf16 = 16 MiB aliases Xb+W1T (L2 reads only Hbuf/W2T;
  // prep fully rewrites Xb/W1T next call -> deterministic).
  unsigned short* Ybuf = (unsigned short*)(ws + 0);

  prep_kernel<<<18432, 256, 0, stream>>>(inp, w1, w2, gw, gb,
                                         Xb, W1T, W2T, eidx, wgtA);
  build_lists<<<NE, 256, 0, stream>>>(eidx, lists, counts);
  // L1: 8e x (32rt x 16ct) = 4096 blocks worst-case; ~512 active
  moe_gemm<DM, HD, true, 1><<<8 * 32 * (HD / 128), 512, 0, stream>>>(
      Xb, W1T, b1, lists, counts, Hbuf);
  // L2: 8e x (32rt x 2ks x 4ct) = 2048 blocks worst-case; ~256 active
  moe_gemm<HD, DM, false, 2><<<8 * 32 * 2 * (DM / 128), 512, 0, stream>>>(
      Hbuf, W2T, b2, lists, counts, Ybuf);
  combine_kernel<<<NTOK / 4, 256, 0, stream>>>(Ybuf, b2, eidx, wgtA, out);
}